// Round 2
// 159.377 us; speedup vs baseline: 1.2411x; 1.2411x over previous
//
#include <hip/hip_runtime.h>

#define NN 20
#define ST64 22        // fp64 stride: rows 176B, 16B-aligned (double2-friendly)
#define ST32 20        // fp32 stride: rows 80B, 16B-aligned (float4-friendly)
#define N2 400
#define MM 440
// Hybrid precision schedule [R1 post-mortem]:
//   Pure fp64 K=18: absmax 1.35e-3 (R0, validated).
//   Pure fp32 K=18: absmax 0.168 = effective progress ~15.9 iters -> fp32 loses
//   ~2.1 iters to late-stage alpha degradation (ratio-test noise once mu_elem
//   approaches fp32 noise floor), but tracks the fp64 trajectory fine early on.
//   IPM is self-correcting (noise at iter k contracts ~10x per later accurate
//   step) -> run first 12 iters fp32, last 6 iters fp64 (validated R0 body).
// Predicted absmax ~1.5-3e-3 (threshold 2e-2).
#define K32 12
#define K64 6

// single-wave block + per-wave in-order LDS pipeline => compiler fence suffices
#define FENCE() asm volatile("" ::: "memory")

// ---------- fp64 helpers (R0, validated) ----------
__device__ __forceinline__ double drcp(double x) {
  double r = __builtin_amdgcn_rcp(x);       // v_rcp_f64 seed
  r = fma(r, fma(-x, r, 1.0), r);           // NR 1
  r = fma(r, fma(-x, r, 1.0), r);           // NR 2 -> ~1 ulp
  return r;
}
__device__ __forceinline__ double dreadlane(double v, int lane) {
  int lo = __builtin_amdgcn_readlane(__double2loint(v), lane);
  int hi = __builtin_amdgcn_readlane(__double2hiint(v), lane);
  return __hiloint2double(hi, lo);
}
__device__ __forceinline__ double fair_d(int c) {
  return (c < 8) ? 0.125 : (double)(-1.0f / 12.0f);  // matches fp32 ref constant
}
// ---------- fp32 helpers (R1) ----------
__device__ __forceinline__ float frcp(float x) {
  float r = __builtin_amdgcn_rcpf(x);       // v_rcp_f32 seed
  r = fmaf(r, fmaf(-x, r, 1.0f), r);        // 1 NR -> div-grade
  return r;
}
__device__ __forceinline__ float freadlane(float v, int lane) {
  return __int_as_float(__builtin_amdgcn_readlane(__float_as_int(v), lane));
}
__device__ __forceinline__ float wsumf(float v) {
#pragma unroll
  for (int off = 32; off > 0; off >>= 1) v += __shfl_xor(v, off, 64);
  return v;
}
__device__ __forceinline__ float fair_f(int c) {
  return (c < 8) ? 0.125f : (-1.0f / 12.0f);
}

__global__ __launch_bounds__(64, 1) void ipm_kernel(const float* __restrict__ x,
                                                    float* __restrict__ out) {
  const int b = blockIdx.x;
  const int t = threadIdx.x;

  // fp64-sized buffers; fp32 phase aliases the same storage (tiles are
  // written before read within every iteration -> no stale-typed reads).
  __shared__ __align__(16) double phim64[NN * ST64];
  __shared__ __align__(16) double phimT64[NN * ST64];
  __shared__ __align__(16) double y1m64[NN * ST64];
  __shared__ __align__(16) double y1T64[NN * ST64];
  __shared__ __align__(16) double SmX64[ST64 * ST64];  // rows 0..19: S; 20/21: rb1/rb2
  __shared__ __align__(16) double bev64[2 * NN];       // interleaved (be1[c], be2[c])

  float* const phim32  = reinterpret_cast<float*>(phim64);
  float* const phimT32 = reinterpret_cast<float*>(phimT64);
  float* const y1m32   = reinterpret_cast<float*>(y1m64);
  float* const y1T32   = reinterpret_cast<float*>(y1T64);
  float* const SmX32   = reinterpret_cast<float*>(SmX64);
  float* const bev32   = reinterpret_cast<float*>(bev64);

  // 2x2 Schur block decode (triangular, 55 blocks), once per kernel
  int bc_, bp_;
  {
    int bid = t, c = 0;
#pragma unroll
    for (int q = 0; q < 9; ++q) {
      if (c < 9 && bid >= 10 - c) { bid -= 10 - c; ++c; }
    }
    bp_ = (t < 55) ? (c + bid) : 0;
    bc_ = (t < 55) ? c : 0;
  }

  int rr_[7], cc_[7];
  float pf[7];

  // ---- fp32 state (phase 1) ----
  float zf[7], slf[7];
  float lreq0 = 0.f;
#pragma unroll
  for (int j = 0; j < 7; ++j) {
    int i = t + 64 * j;
    pf[j] = (i < N2) ? x[b * N2 + i] : 0.0f;
    if (i < N2) {
      int r = i / NN, c = i - (i / NN) * NN;
      rr_[j] = r; cc_[j] = c;
      zf[j] = 0.025f;
      slf[j] = 1.0f;
      lreq0 += fair_f(c) * 0.025f;
    } else { rr_[j] = 0; cc_[j] = 0; zf[j] = 0.025f; slf[j] = 1.0f; }
  }
  float reqf = wsumf(lreq0);
  float s1f = 0.5f, l1f = 1.0f;
  float nuf = 0.f;
  float musumf = 30.0f;                 // exact: 40*0.5 + 400*0.025
  float smuf = 0.1f * musumf * (1.0f / MM);

  // =====================================================================
  // PHASE 1: K32 iterations in fp32 (R1 body, verbatim)
  // =====================================================================
  {
    const float EPSf = 1e-4f;
    float srs[7], rl[7], phir[7], y1r[7], du1[7], du2[7], dzr[7], sdl[7];
    float s1 = s1f, l1 = l1f, rs1 = 0.f, ds1 = 0.f, dl1 = 0.f, invd = 0.f, gl1 = 0.f;
    float e0 = 0.f, e1 = 0.f, e2 = 0.f, D1iloc = 0.f;
    float W1 = 0.f, W2 = 0.f, sumdz = 0.f;
    float nu = nuf, req = reqf, musum = musumf, smu = smuf;

#pragma unroll 1
    for (int it = 0; it < K32; ++it) {
      // ---- C: per-constraint scalars, element recips
      {
        float s1c = (t < 40) ? s1 : 1.0f;
        float l1c = (t < 40) ? l1 : 1.0f;
        rs1 = frcp(s1c);
        gl1 = smu * rs1;
        invd = s1c * frcp(l1c);
      }
#pragma unroll
      for (int j = 0; j < 7; ++j) {
        srs[j] = frcp(zf[j]);
        rl[j] = frcp(slf[j]);
        phir[j] = zf[j] * frcp(fmaf(EPSf, zf[j], slf[j]));
      }

      // ---- D: y1 = rhs_z; gl broadcast by shfl; store tiles
#pragma unroll
      for (int j = 0; j < 7; ++j) {
        int r = rr_[j], c = cc_[j];
        float glr = __shfl(gl1, r);
        float glc = __shfl(gl1, NN + c);
        int i = t + 64 * j;
        if (i < N2) {
          float pv = -pf[j];
          float y = -(EPSf * zf[j] + pv + nu * fair_f(c)
                      + glr + glc - smu * srs[j]);
          y1r[j] = y;
          phim32[r * ST32 + c] = phir[j];
          phimT32[c * ST32 + r] = phir[j];
          y1m32[r * ST32 + c] = y;
          y1T32[c * ST32 + r] = y;
        }
      }
      FENCE();

      // ---- E+G merged: reductions, then Schur
      if (t < 40) {
        const bool isrow = (t < NN);
        const int rc = isrow ? t : (t - NN);
        const float4* pb = reinterpret_cast<const float4*>(isrow ? &phim32[rc * ST32] : &phimT32[rc * ST32]);
        const float4* yb = reinterpret_cast<const float4*>(isrow ? &y1m32[rc * ST32] : &y1T32[rc * ST32]);
        float a0A = 0.f, a0B = 0.f, a0C = 0.f, a0D = 0.f;
        float a1A = 0.f, a1B = 0.f, a1C = 0.f, a1D = 0.f;
        float a2A = 0.f, a2B = 0.f, a2C = 0.f, a2D = 0.f;
#pragma unroll
        for (int jj = 0; jj < 5; ++jj) {
          float4 ph = pb[jj];
          float4 yy = yb[jj];
          a0A += ph.x; a0B += ph.y; a0C += ph.z; a0D += ph.w;
          a1A = fmaf(ph.x, yy.x, a1A); a1B = fmaf(ph.y, yy.y, a1B);
          a1C = fmaf(ph.z, yy.z, a1C); a1D = fmaf(ph.w, yy.w, a1D);
          a2A = fmaf(ph.x, fair_f(4 * jj), a2A);
          a2B = fmaf(ph.y, fair_f(4 * jj + 1), a2B);
          a2C = fmaf(ph.z, fair_f(4 * jj + 2), a2C);
          a2D = fmaf(ph.w, fair_f(4 * jj + 3), a2D);
        }
        e0 = (a0A + a0B) + (a0C + a0D);
        e1 = (a1A + a1B) + (a1C + a1D);
        e2 = (a2A + a2B) + (a2C + a2D);
        if (isrow) D1iloc = frcp(invd + e0);
      }
      float g1loc = 0.f, g2loc = 0.f;
      {
        float D2loc = invd + e0;
        float D2c0 = __shfl(D2loc, NN + 2 * bc_);
        float D2c1 = __shfl(D2loc, NN + 2 * bc_ + 1);
        int cidx0 = NN + (t % NN);
        float t1c = __shfl(e1, cidx0);
        float Ccl = __shfl(e0, cidx0);
        if (t < 55) {
          const int c0 = 2 * bc_, c1i = 2 * bc_ + 1, q0 = 2 * bp_, q1i = 2 * bp_ + 1;
          const float4* pc0 = reinterpret_cast<const float4*>(&phimT32[c0 * ST32]);
          const float4* pc1 = reinterpret_cast<const float4*>(&phimT32[c1i * ST32]);
          const float4* pb0 = reinterpret_cast<const float4*>(&phimT32[q0 * ST32]);
          const float4* pb1 = reinterpret_cast<const float4*>(&phimT32[q1i * ST32]);
          float s00A = 0, s00B = 0, s01A = 0, s01B = 0;
          float s10A = 0, s10B = 0, s11A = 0, s11B = 0;
#pragma unroll
          for (int r = 0; r < 5; ++r) {
            float d0 = freadlane(D1iloc, 4 * r);
            float d1 = freadlane(D1iloc, 4 * r + 1);
            float d2 = freadlane(D1iloc, 4 * r + 2);
            float d3 = freadlane(D1iloc, 4 * r + 3);
            float4 a0 = pc0[r], a1 = pc1[r], b0 = pb0[r], b1 = pb1[r];
            float u0x = a0.x * d0, u0y = a0.y * d1, u0z = a0.z * d2, u0w = a0.w * d3;
            float u1x = a1.x * d0, u1y = a1.y * d1, u1z = a1.z * d2, u1w = a1.w * d3;
            s00A = fmaf(u0x, b0.x, s00A); s00A = fmaf(u0z, b0.z, s00A);
            s00B = fmaf(u0y, b0.y, s00B); s00B = fmaf(u0w, b0.w, s00B);
            s01A = fmaf(u0x, b1.x, s01A); s01A = fmaf(u0z, b1.z, s01A);
            s01B = fmaf(u0y, b1.y, s01B); s01B = fmaf(u0w, b1.w, s01B);
            s10A = fmaf(u1x, b0.x, s10A); s10A = fmaf(u1z, b0.z, s10A);
            s10B = fmaf(u1y, b0.y, s10B); s10B = fmaf(u1w, b0.w, s10B);
            s11A = fmaf(u1x, b1.x, s11A); s11A = fmaf(u1z, b1.z, s11A);
            s11B = fmaf(u1y, b1.y, s11B); s11B = fmaf(u1w, b1.w, s11B);
          }
          float S00 = -(s00A + s00B), S01 = -(s01A + s01B);
          float S10 = -(s10A + s10B), S11 = -(s11A + s11B);
          if (bc_ == bp_) { S00 += D2c0; S11 += D2c1; }
          SmX32[c0 * ST32 + q0] = S00;  SmX32[c0 * ST32 + q1i] = S01;
          SmX32[c1i * ST32 + q0] = S10; SmX32[c1i * ST32 + q1i] = S11;
          if (bc_ != bp_) {
            SmX32[q0 * ST32 + c0] = S00;  SmX32[q1i * ST32 + c0] = S01;
            SmX32[q0 * ST32 + c1i] = S10; SmX32[q1i * ST32 + c1i] = S11;
          }
        }
        if (t < NN) {
          const float4* pa = reinterpret_cast<const float4*>(&phimT32[t * ST32]);
          float a1A = 0.f, a1B = 0.f, a2A = 0.f, a2B = 0.f;
#pragma unroll
          for (int r = 0; r < 5; ++r) {
            float d0 = freadlane(D1iloc, 4 * r);
            float d1 = freadlane(D1iloc, 4 * r + 1);
            float d2 = freadlane(D1iloc, 4 * r + 2);
            float d3 = freadlane(D1iloc, 4 * r + 3);
            float4 u = pa[r];
            float ux = u.x * d0, uy = u.y * d1, uz = u.z * d2, uw = u.w * d3;
            float p1x = freadlane(e1, 4 * r),     p1y = freadlane(e1, 4 * r + 1);
            float p1z = freadlane(e1, 4 * r + 2), p1w = freadlane(e1, 4 * r + 3);
            float p2x = freadlane(e2, 4 * r),     p2y = freadlane(e2, 4 * r + 1);
            float p2z = freadlane(e2, 4 * r + 2), p2w = freadlane(e2, 4 * r + 3);
            a1A = fmaf(ux, p1x, a1A); a1A = fmaf(uz, p1z, a1A);
            a1B = fmaf(uy, p1y, a1B); a1B = fmaf(uw, p1w, a1B);
            a2A = fmaf(ux, p2x, a2A); a2A = fmaf(uz, p2z, a2A);
            a2B = fmaf(uy, p2y, a2B); a2B = fmaf(uw, p2w, a2B);
          }
          g1loc = a1A + a1B; g2loc = a2A + a2B;
          SmX32[20 * ST32 + t] = t1c - g1loc;
          SmX32[21 * ST32 + t] = fair_f(t) * Ccl - g2loc;
        }
      }
      FENCE();

      // ---- H: 2x2 block Gauss-Jordan
      {
        float B[NN];
        {
          int rowi = (t < NN + 2) ? t : 0;
          const float4* srcr = reinterpret_cast<const float4*>(&SmX32[rowi * ST32]);
#pragma unroll
          for (int k4 = 0; k4 < 5; ++k4) {
            float4 v = srcr[k4];
            B[4 * k4] = v.x; B[4 * k4 + 1] = v.y; B[4 * k4 + 2] = v.z; B[4 * k4 + 3] = v.w;
          }
        }
        float a = freadlane(B[0], 0), bb = freadlane(B[0], 1);
        float c = freadlane(B[1], 0), d = freadlane(B[1], 1);
        float rdet = frcp(fmaf(a, d, -(bb * c)));
#pragma unroll
        for (int p = 0; p < 10; ++p) {
          const int k = 2 * p;
          float t0 = d * B[k];       t0 = fmaf(-bb, B[k + 1], t0);
          float rk = t0 * rdet;
          float t1 = a * B[k + 1];   t1 = fmaf(-c, B[k], t1);
          float rk1 = t1 * rdet;
          if (p < 9) {
            float u0 = freadlane(B[k + 2], k), u1 = freadlane(B[k + 2], k + 1);
            B[k + 2] = fmaf(-u0, rk, B[k + 2]); B[k + 2] = fmaf(-u1, rk1, B[k + 2]);
            float v0 = freadlane(B[k + 3], k), v1 = freadlane(B[k + 3], k + 1);
            B[k + 3] = fmaf(-v0, rk, B[k + 3]); B[k + 3] = fmaf(-v1, rk1, B[k + 3]);
            a = freadlane(B[k + 2], k + 2); bb = freadlane(B[k + 2], k + 3);
            c = freadlane(B[k + 3], k + 2); d = freadlane(B[k + 3], k + 3);
            rdet = frcp(fmaf(a, d, -(bb * c)));
          }
#pragma unroll
          for (int i2 = 0; i2 < NN; ++i2) {
            if (i2 != k && i2 != k + 1 && !(p < 9 && (i2 == k + 2 || i2 == k + 3))) {
              float ci0 = freadlane(B[i2], k), ci1 = freadlane(B[i2], k + 1);
              B[i2] = fmaf(-ci0, rk, B[i2]);
              B[i2] = fmaf(-ci1, rk1, B[i2]);
            }
          }
          B[k] = rk; B[k + 1] = rk1;
        }
        if (t == NN || t == NN + 1) {
          int off = t - NN;
#pragma unroll
          for (int i2 = 0; i2 < NN; ++i2) bev32[2 * i2 + off] = B[i2];
        }
      }
      FENCE();

      // ---- I+J merged
      float PB1 = 0.f, PB2 = 0.f, a1rloc = 0.f, a2rloc = 0.f;
      {
        int cidx = (t >= NN && t < 2 * NN) ? (t - NN) : 0;
        float g1c = __shfl(g1loc, cidx);
        float g2c = __shfl(g2loc, cidx);
        if (t < NN) {
          const float4* pa = reinterpret_cast<const float4*>(&phim32[t * ST32]);
          const float4* bv = reinterpret_cast<const float4*>(bev32);
          float b1A = 0.f, b1B = 0.f, b2A = 0.f, b2B = 0.f;
#pragma unroll
          for (int c2 = 0; c2 < 5; ++c2) {
            float4 ph = pa[c2];
            float4 e0b = bv[2 * c2];
            float4 e1b = bv[2 * c2 + 1];
            b1A = fmaf(ph.x, e0b.x, b1A); b2A = fmaf(ph.x, e0b.y, b2A);
            b1B = fmaf(ph.y, e0b.z, b1B); b2B = fmaf(ph.y, e0b.w, b2B);
            b1A = fmaf(ph.z, e1b.x, b1A); b2A = fmaf(ph.z, e1b.y, b2A);
            b1B = fmaf(ph.w, e1b.z, b1B); b2B = fmaf(ph.w, e1b.w, b2B);
          }
          PB1 = b1A + b1B; PB2 = b2A + b2B;
          a1rloc = (e1 - PB1) * D1iloc;
          a2rloc = (e2 - PB2) * D1iloc;
          W1 = e1 - e0 * a1rloc - PB1;
          W2 = e2 - e0 * a2rloc - PB2;
        }
        if (t >= NN && t < 2 * NN) {
          int c = t - NN;
          const float4* pa = reinterpret_cast<const float4*>(&phimT32[c * ST32]);
          float c1A = 0.f, c1B = 0.f, c2A = 0.f, c2B = 0.f;
#pragma unroll
          for (int r = 0; r < 5; ++r) {
            float d0 = freadlane(D1iloc, 4 * r);
            float d1 = freadlane(D1iloc, 4 * r + 1);
            float d2 = freadlane(D1iloc, 4 * r + 2);
            float d3 = freadlane(D1iloc, 4 * r + 3);
            float4 u = pa[r];
            float ux = u.x * d0, uy = u.y * d1, uz = u.z * d2, uw = u.w * d3;
            float pb1x = freadlane(PB1, 4 * r),     pb1y = freadlane(PB1, 4 * r + 1);
            float pb1z = freadlane(PB1, 4 * r + 2), pb1w = freadlane(PB1, 4 * r + 3);
            float pb2x = freadlane(PB2, 4 * r),     pb2y = freadlane(PB2, 4 * r + 1);
            float pb2z = freadlane(PB2, 4 * r + 2), pb2w = freadlane(PB2, 4 * r + 3);
            c1A = fmaf(ux, pb1x, c1A); c1A = fmaf(uz, pb1z, c1A);
            c1B = fmaf(uy, pb1y, c1B); c1B = fmaf(uw, pb1w, c1B);
            c2A = fmaf(ux, pb2x, c2A); c2A = fmaf(uz, pb2z, c2A);
            c2B = fmaf(uy, pb2y, c2B); c2B = fmaf(uw, pb2w, c2B);
          }
          float A1 = g1c - (c1A + c1B);
          float A2 = g2c - (c2A + c2B);
          const float2* bv2 = reinterpret_cast<const float2*>(bev32);
          float2 bec = bv2[c];
          W1 = e1 - A1 - e0 * bec.x;
          W2 = e0 * fair_f(c) - A2 - e0 * bec.y;
        }
      }
#pragma unroll
      for (int j = 0; j < 7; ++j) {
        float a1e = __shfl(a1rloc, rr_[j]);
        float a2e = __shfl(a2rloc, rr_[j]);
        int i = t + 64 * j;
        if (i < N2) {
          const float2* bv2 = reinterpret_cast<const float2*>(bev32);
          float2 bec = bv2[cc_[j]];
          du1[j] = phir[j] * (y1r[j] - a1e - bec.x);
          du2[j] = phir[j] * (fair_f(cc_[j]) - a2e - bec.y);
        }
      }
      float dnu;
      {
        float sA = 0.f, sB = 0.f, uA = 0.f, uB = 0.f;
#pragma unroll
        for (int c2 = 0; c2 < NN; c2 += 2) {
          sA = fmaf(fair_f(c2),     freadlane(W1, NN + c2),     sA);
          sB = fmaf(fair_f(c2 + 1), freadlane(W1, NN + c2 + 1), sB);
          uA = fmaf(fair_f(c2),     freadlane(W2, NN + c2),     uA);
          uB = fmaf(fair_f(c2 + 1), freadlane(W2, NN + c2 + 1), uB);
        }
        dnu = ((sA + sB) + req) * frcp(uA + uB);
      }
      if (t < 40) sumdz = W1 - dnu * W2;

      // ---- M: dz, dlam, max-ratio, T1/T2
      float maxr = 0.f, T1 = 0.f, T2 = 0.f;
      if (t < 40) {
        ds1 = -sumdz;
        dl1 = (smu - s1 * l1 - l1 * ds1) * rs1;
        maxr = fmaxf(maxr, -ds1 * rs1);
        maxr = fmaxf(maxr, -dl1 * (rs1 * invd));
        T1 = s1 * dl1 + l1 * ds1;
        T2 = ds1 * dl1;
      }
#pragma unroll
      for (int j = 0; j < 7; ++j) {
        int i = t + 64 * j;
        if (i < N2) {
          float dz = du1[j] - dnu * du2[j];
          dzr[j] = dz;
          float dl = (smu - zf[j] * slf[j] - slf[j] * dz) * srs[j];
          sdl[j] = dl;
          maxr = fmaxf(maxr, -dz * srs[j]);
          maxr = fmaxf(maxr, -dl * rl[j]);
          T1 += zf[j] * dl + slf[j] * dz;
          T2 += dz * dl;
        }
      }
#pragma unroll
      for (int off = 32; off >= 8; off >>= 1) {
        maxr = fmaxf(maxr, __shfl_xor(maxr, off, 64));
        T1 += __shfl_xor(T1, off, 64);
        T2 += __shfl_xor(T2, off, 64);
      }
      {
        float m0 = 0.f, sT1A = 0.f, sT1B = 0.f, sT2A = 0.f, sT2B = 0.f;
#pragma unroll
        for (int l = 0; l < 8; l += 2) {
          m0 = fmaxf(m0, fmaxf(freadlane(maxr, l), freadlane(maxr, l + 1)));
          sT1A += freadlane(T1, l); sT1B += freadlane(T1, l + 1);
          sT2A += freadlane(T2, l); sT2B += freadlane(T2, l + 1);
        }
        maxr = m0; T1 = sT1A + sT1B; T2 = sT2A + sT2B;
      }
      const float alpha = fminf(1.0f, 0.99f * frcp(maxr));

      // ---- N: updates + recurrences
#pragma unroll
      for (int j = 0; j < 7; ++j) {
        int i = t + 64 * j;
        if (i < N2) {
          zf[j] = fmaf(alpha, dzr[j], zf[j]);
          slf[j] = fmaf(alpha, sdl[j], slf[j]);
        }
      }
      if (t < 40) {
        s1 = fmaf(alpha, ds1, s1);
        l1 = fmaf(alpha, dl1, l1);
      }
      nu = fmaf(alpha, dnu, nu);
      req *= (1.0f - alpha);
      musum = fmaf(alpha * alpha, T2, fmaf(alpha, T1, musum));
      smu = 0.1f * musum * (1.0f / MM);
      FENCE();
    }
    s1f = s1; l1f = l1; nuf = nu; reqf = req; musumf = musum; smuf = smu;
  }

  // =====================================================================
  // State conversion fp32 -> fp64
  // =====================================================================
  double zr[7], sl[7];
#pragma unroll
  for (int j = 0; j < 7; ++j) { zr[j] = (double)zf[j]; sl[j] = (double)slf[j]; }
  double s1 = (double)s1f, l1 = (double)l1f;
  double nu = (double)nuf;
  double req = (double)reqf;
  double musum = (double)musumf;
  double smu = 0.1 * musum * (1.0 / MM);
  FENCE();

  // =====================================================================
  // PHASE 2: K64 iterations in fp64 (R0 body, verbatim)
  // =====================================================================
  {
    const double EPSd = 1e-4, SIG = 0.1;
    double srs[7], rl[7], phir[7], y1r[7], du1[7], du2[7], dzr[7], sdl[7];
    double rs1 = 0.0, ds1 = 0.0, dl1 = 0.0, invd = 0.0, gl1 = 0.0;
    double e0 = 0.0, e1 = 0.0, e2 = 0.0, D1iloc = 0.0;
    double W1 = 0.0, W2 = 0.0, sumdz = 0.0;

#pragma unroll 1
    for (int it = 0; it < K64; ++it) {
      // ---- C
      {
        double s1c = (t < 40) ? s1 : 1.0;
        double l1c = (t < 40) ? l1 : 1.0;
        rs1 = drcp(s1c);
        gl1 = smu * rs1;
        invd = s1c * drcp(l1c);
      }
#pragma unroll
      for (int j = 0; j < 7; ++j) {
        srs[j] = drcp(zr[j]);
        rl[j] = drcp(sl[j]);
        phir[j] = zr[j] * drcp(fma(EPSd, zr[j], sl[j]));
      }

      // ---- D
#pragma unroll
      for (int j = 0; j < 7; ++j) {
        int r = rr_[j], c = cc_[j];
        double glr = __shfl(gl1, r);
        double glc = __shfl(gl1, NN + c);
        int i = t + 64 * j;
        if (i < N2) {
          double pv = -(double)pf[j];
          double y = -(EPSd * zr[j] + pv + nu * fair_d(c)
                       + glr + glc - smu * srs[j]);
          y1r[j] = y;
          phim64[r * ST64 + c] = phir[j];
          phimT64[c * ST64 + r] = phir[j];
          y1m64[r * ST64 + c] = y;
          y1T64[c * ST64 + r] = y;
        }
      }
      FENCE();

      // ---- E+G merged
      if (t < 40) {
        const bool isrow = (t < NN);
        const int rc = isrow ? t : (t - NN);
        const double2* pb = reinterpret_cast<const double2*>(isrow ? &phim64[rc * ST64] : &phimT64[rc * ST64]);
        const double2* yb = reinterpret_cast<const double2*>(isrow ? &y1m64[rc * ST64] : &y1T64[rc * ST64]);
        double a0A = 0.0, a0B = 0.0, a1A = 0.0, a1B = 0.0, a2A = 0.0, a2B = 0.0;
#pragma unroll
        for (int jj = 0; jj < 10; ++jj) {
          double2 ph = pb[jj];
          double2 yy = yb[jj];
          a0A += ph.x;                 a0B += ph.y;
          a1A = fma(ph.x, yy.x, a1A);  a1B = fma(ph.y, yy.y, a1B);
          a2A = fma(ph.x, fair_d(2 * jj), a2A);
          a2B = fma(ph.y, fair_d(2 * jj + 1), a2B);
        }
        e0 = a0A + a0B; e1 = a1A + a1B; e2 = a2A + a2B;
        if (isrow) D1iloc = drcp(invd + e0);
      }
      double g1loc = 0.0, g2loc = 0.0;
      {
        double D2loc = invd + e0;
        double D2c0 = __shfl(D2loc, NN + 2 * bc_);
        double D2c1 = __shfl(D2loc, NN + 2 * bc_ + 1);
        int cidx0 = NN + (t % NN);
        double t1c = __shfl(e1, cidx0);
        double Ccl = __shfl(e0, cidx0);
        if (t < 55) {
          const int c0 = 2 * bc_, c1i = 2 * bc_ + 1, q0 = 2 * bp_, q1i = 2 * bp_ + 1;
          const double2* pc0 = reinterpret_cast<const double2*>(&phimT64[c0 * ST64]);
          const double2* pc1 = reinterpret_cast<const double2*>(&phimT64[c1i * ST64]);
          const double2* pb0 = reinterpret_cast<const double2*>(&phimT64[q0 * ST64]);
          const double2* pb1 = reinterpret_cast<const double2*>(&phimT64[q1i * ST64]);
          double s00A = 0, s00B = 0, s01A = 0, s01B = 0;
          double s10A = 0, s10B = 0, s11A = 0, s11B = 0;
#pragma unroll
          for (int r = 0; r < 10; ++r) {
            double ddx = dreadlane(D1iloc, 2 * r);
            double ddy = dreadlane(D1iloc, 2 * r + 1);
            double2 a0 = pc0[r], a1 = pc1[r], b0 = pb0[r], b1 = pb1[r];
            double u0x = a0.x * ddx, u0y = a0.y * ddy;
            double u1x = a1.x * ddx, u1y = a1.y * ddy;
            s00A = fma(u0x, b0.x, s00A); s00B = fma(u0y, b0.y, s00B);
            s01A = fma(u0x, b1.x, s01A); s01B = fma(u0y, b1.y, s01B);
            s10A = fma(u1x, b0.x, s10A); s10B = fma(u1y, b0.y, s10B);
            s11A = fma(u1x, b1.x, s11A); s11B = fma(u1y, b1.y, s11B);
          }
          double S00 = -(s00A + s00B), S01 = -(s01A + s01B);
          double S10 = -(s10A + s10B), S11 = -(s11A + s11B);
          if (bc_ == bp_) { S00 += D2c0; S11 += D2c1; }
          SmX64[c0 * ST64 + q0] = S00;  SmX64[c0 * ST64 + q1i] = S01;
          SmX64[c1i * ST64 + q0] = S10; SmX64[c1i * ST64 + q1i] = S11;
          if (bc_ != bp_) {
            SmX64[q0 * ST64 + c0] = S00;  SmX64[q1i * ST64 + c0] = S01;
            SmX64[q0 * ST64 + c1i] = S10; SmX64[q1i * ST64 + c1i] = S11;
          }
        }
        if (t < NN) {
          const double2* pa = reinterpret_cast<const double2*>(&phimT64[t * ST64]);
          double a1A = 0.0, a1B = 0.0, a2A = 0.0, a2B = 0.0;
#pragma unroll
          for (int r = 0; r < 10; ++r) {
            double ddx = dreadlane(D1iloc, 2 * r);
            double ddy = dreadlane(D1iloc, 2 * r + 1);
            double2 u = pa[r];
            double ux = u.x * ddx, uy = u.y * ddy;
            double p1x = dreadlane(e1, 2 * r), p1y = dreadlane(e1, 2 * r + 1);
            double p2x = dreadlane(e2, 2 * r), p2y = dreadlane(e2, 2 * r + 1);
            a1A = fma(ux, p1x, a1A); a1B = fma(uy, p1y, a1B);
            a2A = fma(ux, p2x, a2A); a2B = fma(uy, p2y, a2B);
          }
          g1loc = a1A + a1B; g2loc = a2A + a2B;
          SmX64[20 * ST64 + t] = t1c - g1loc;
          SmX64[21 * ST64 + t] = fair_d(t) * Ccl - g2loc;
        }
      }
      FENCE();

      // ---- H
      {
        double B[NN];
        {
          int rowi = (t < NN + 2) ? t : 0;
          const double2* srcr = reinterpret_cast<const double2*>(&SmX64[rowi * ST64]);
#pragma unroll
          for (int k2 = 0; k2 < 10; ++k2) {
            double2 v = srcr[k2];
            B[2 * k2] = v.x; B[2 * k2 + 1] = v.y;
          }
        }
        double a = dreadlane(B[0], 0), bb = dreadlane(B[0], 1);
        double c = dreadlane(B[1], 0), d = dreadlane(B[1], 1);
        double rdet = drcp(fma(a, d, -(bb * c)));
#pragma unroll
        for (int p = 0; p < 10; ++p) {
          const int k = 2 * p;
          double t0 = d * B[k];       t0 = fma(-bb, B[k + 1], t0);
          double rk = t0 * rdet;
          double t1 = a * B[k + 1];   t1 = fma(-c, B[k], t1);
          double rk1 = t1 * rdet;
          if (p < 9) {
            double u0 = dreadlane(B[k + 2], k), u1 = dreadlane(B[k + 2], k + 1);
            B[k + 2] = fma(-u0, rk, B[k + 2]); B[k + 2] = fma(-u1, rk1, B[k + 2]);
            double v0 = dreadlane(B[k + 3], k), v1 = dreadlane(B[k + 3], k + 1);
            B[k + 3] = fma(-v0, rk, B[k + 3]); B[k + 3] = fma(-v1, rk1, B[k + 3]);
            a = dreadlane(B[k + 2], k + 2); bb = dreadlane(B[k + 2], k + 3);
            c = dreadlane(B[k + 3], k + 2); d = dreadlane(B[k + 3], k + 3);
            rdet = drcp(fma(a, d, -(bb * c)));
          }
#pragma unroll
          for (int i2 = 0; i2 < NN; ++i2) {
            if (i2 != k && i2 != k + 1 && !(p < 9 && (i2 == k + 2 || i2 == k + 3))) {
              double ci0 = dreadlane(B[i2], k), ci1 = dreadlane(B[i2], k + 1);
              B[i2] = fma(-ci0, rk, B[i2]);
              B[i2] = fma(-ci1, rk1, B[i2]);
            }
          }
          B[k] = rk; B[k + 1] = rk1;
        }
        if (t == NN || t == NN + 1) {
          int off = t - NN;
#pragma unroll
          for (int i2 = 0; i2 < NN; ++i2) bev64[2 * i2 + off] = B[i2];
        }
      }
      FENCE();

      // ---- I+J merged
      double PB1 = 0.0, PB2 = 0.0, a1rloc = 0.0, a2rloc = 0.0;
      {
        int cidx = (t >= NN && t < 2 * NN) ? (t - NN) : 0;
        double g1c = __shfl(g1loc, cidx);
        double g2c = __shfl(g2loc, cidx);
        if (t < NN) {
          const double2* pa = reinterpret_cast<const double2*>(&phim64[t * ST64]);
          const double2* bv = reinterpret_cast<const double2*>(bev64);
          double b1A = 0.0, b1B = 0.0, b2A = 0.0, b2B = 0.0;
#pragma unroll
          for (int c2 = 0; c2 < 10; ++c2) {
            double2 ph = pa[c2];
            double2 e0b = bv[2 * c2];
            double2 e1b = bv[2 * c2 + 1];
            b1A = fma(ph.x, e0b.x, b1A); b2A = fma(ph.x, e0b.y, b2A);
            b1B = fma(ph.y, e1b.x, b1B); b2B = fma(ph.y, e1b.y, b2B);
          }
          PB1 = b1A + b1B; PB2 = b2A + b2B;
          a1rloc = (e1 - PB1) * D1iloc;
          a2rloc = (e2 - PB2) * D1iloc;
          W1 = e1 - e0 * a1rloc - PB1;
          W2 = e2 - e0 * a2rloc - PB2;
        }
        if (t >= NN && t < 2 * NN) {
          int c = t - NN;
          const double2* pa = reinterpret_cast<const double2*>(&phimT64[c * ST64]);
          double c1A = 0.0, c1B = 0.0, c2A = 0.0, c2B = 0.0;
#pragma unroll
          for (int r = 0; r < 10; ++r) {
            double ddx = dreadlane(D1iloc, 2 * r);
            double ddy = dreadlane(D1iloc, 2 * r + 1);
            double2 u = pa[r];
            double ux = u.x * ddx, uy = u.y * ddy;
            double pb1x = dreadlane(PB1, 2 * r), pb1y = dreadlane(PB1, 2 * r + 1);
            double pb2x = dreadlane(PB2, 2 * r), pb2y = dreadlane(PB2, 2 * r + 1);
            c1A = fma(ux, pb1x, c1A); c1B = fma(uy, pb1y, c1B);
            c2A = fma(ux, pb2x, c2A); c2B = fma(uy, pb2y, c2B);
          }
          double A1 = g1c - (c1A + c1B);
          double A2 = g2c - (c2A + c2B);
          const double2* bv = reinterpret_cast<const double2*>(bev64);
          double2 bec = bv[c];
          W1 = e1 - A1 - e0 * bec.x;
          W2 = e0 * fair_d(c) - A2 - e0 * bec.y;
        }
      }
#pragma unroll
      for (int j = 0; j < 7; ++j) {
        double a1e = __shfl(a1rloc, rr_[j]);
        double a2e = __shfl(a2rloc, rr_[j]);
        int i = t + 64 * j;
        if (i < N2) {
          const double2* bv = reinterpret_cast<const double2*>(bev64);
          double2 bec = bv[cc_[j]];
          du1[j] = phir[j] * (y1r[j] - a1e - bec.x);
          du2[j] = phir[j] * (fair_d(cc_[j]) - a2e - bec.y);
        }
      }
      double dnu;
      {
        double sA = 0.0, sB = 0.0, uA = 0.0, uB = 0.0;
#pragma unroll
        for (int c2 = 0; c2 < NN; c2 += 2) {
          sA = fma(fair_d(c2),     dreadlane(W1, NN + c2),     sA);
          sB = fma(fair_d(c2 + 1), dreadlane(W1, NN + c2 + 1), sB);
          uA = fma(fair_d(c2),     dreadlane(W2, NN + c2),     uA);
          uB = fma(fair_d(c2 + 1), dreadlane(W2, NN + c2 + 1), uB);
        }
        dnu = ((sA + sB) + req) * drcp(uA + uB);
      }
      if (t < 40) sumdz = W1 - dnu * W2;

      // ---- M
      double maxr = 0.0, T1 = 0.0, T2 = 0.0;
      if (t < 40) {
        ds1 = -sumdz;
        dl1 = (smu - s1 * l1 - l1 * ds1) * rs1;
        maxr = fmax(maxr, -ds1 * rs1);
        maxr = fmax(maxr, -dl1 * (rs1 * invd));
        T1 = s1 * dl1 + l1 * ds1;
        T2 = ds1 * dl1;
      }
#pragma unroll
      for (int j = 0; j < 7; ++j) {
        int i = t + 64 * j;
        if (i < N2) {
          double dz = du1[j] - dnu * du2[j];
          dzr[j] = dz;
          double dl = (smu - zr[j] * sl[j] - sl[j] * dz) * srs[j];
          sdl[j] = dl;
          maxr = fmax(maxr, -dz * srs[j]);
          maxr = fmax(maxr, -dl * rl[j]);
          T1 += zr[j] * dl + sl[j] * dz;
          T2 += dz * dl;
        }
      }
#pragma unroll
      for (int off = 32; off >= 8; off >>= 1) {
        maxr = fmax(maxr, __shfl_xor(maxr, off, 64));
        T1 += __shfl_xor(T1, off, 64);
        T2 += __shfl_xor(T2, off, 64);
      }
      {
        double m0 = 0.0, sT1A = 0.0, sT1B = 0.0, sT2A = 0.0, sT2B = 0.0;
#pragma unroll
        for (int l = 0; l < 8; l += 2) {
          m0 = fmax(m0, fmax(dreadlane(maxr, l), dreadlane(maxr, l + 1)));
          sT1A += dreadlane(T1, l); sT1B += dreadlane(T1, l + 1);
          sT2A += dreadlane(T2, l); sT2B += dreadlane(T2, l + 1);
        }
        maxr = m0; T1 = sT1A + sT1B; T2 = sT2A + sT2B;
      }
      const double alpha = fmin(1.0, 0.99 * drcp(maxr));

      // ---- N
#pragma unroll
      for (int j = 0; j < 7; ++j) {
        int i = t + 64 * j;
        if (i < N2) {
          zr[j] = fma(alpha, dzr[j], zr[j]);
          sl[j] = fma(alpha, sdl[j], sl[j]);
        }
      }
      if (t < 40) {
        s1 = fma(alpha, ds1, s1);
        l1 = fma(alpha, dl1, l1);
      }
      nu = fma(alpha, dnu, nu);
      req *= (1.0 - alpha);
      musum = fma(alpha * alpha, T2, fma(alpha, T1, musum));
      smu = SIG * musum * (1.0 / MM);
      FENCE();
    }
  }

#pragma unroll
  for (int j = 0; j < 7; ++j) {
    int i = t + 64 * j;
    if (i < N2) out[b * N2 + i] = (float)zr[j];
  }
}

extern "C" void kernel_launch(void* const* d_in, const int* in_sizes, int n_in,
                              void* d_out, int out_size, void* d_ws, size_t ws_size,
                              hipStream_t stream) {
  const float* x = (const float*)d_in[0];
  float* out = (float*)d_out;
  hipLaunchKernelGGL(ipm_kernel, dim3(32), dim3(64), 0, stream, x, out);
}